// Round 7
// baseline (480.708 us; speedup 1.0000x reference)
//
#include <hip/hip_runtime.h>
#include <hip/hip_cooperative_groups.h>
#include <math.h>

namespace cg = cooperative_groups;

// Problem constants
constexpr int Bn = 8, Tn = 32;
constexpr int D_INNER = 512;

typedef __attribute__((ext_vector_type(8))) short short8;   // 8 bf16
typedef __attribute__((ext_vector_type(8))) unsigned short ushort8;
typedef __attribute__((ext_vector_type(4))) float f32x4;

__device__ inline unsigned short f2bf(float x) {
    unsigned int u = __float_as_uint(x);
    unsigned int r = (u + 0x7FFF + ((u >> 16) & 1)) >> 16;  // RNE
    return (unsigned short)r;
}

// 4x4 matrix helpers on 16-lane groups (lane = i*4+j within group)
__device__ __forceinline__ float kf_mm(float Av, float Bv, int i, int j, int gb) {
    float c = 0.f;
    #pragma unroll
    for (int k = 0; k < 4; ++k)
        c = fmaf(__shfl(Av, gb + i * 4 + k, 64), __shfl(Bv, gb + k * 4 + j, 64), c);
    return c;
}
__device__ __forceinline__ float kf_mmT(float Av, float Bv, int i, int j, int gb) {
    float c = 0.f;
    #pragma unroll
    for (int k = 0; k < 4; ++k)
        c = fmaf(__shfl(Av, gb + i * 4 + k, 64), __shfl(Bv, gb + j * 4 + k, 64), c);
    return c;
}

// ---------------------------------------------------------------------------
// ONE prep kernel: conv bf16 weight packs + tail-weight transposes +
// measurement-independent Kalman gain sequence K_t (extra block).
// ---------------------------------------------------------------------------
__global__ void prep_all(
    const float* __restrict__ cw0, const float* __restrict__ cw1,
    const float* __restrict__ cw2,
    const float* __restrict__ ip, const float* __restrict__ xp,
    const float* __restrict__ dt, const float* __restrict__ op,
    const float* __restrict__ h1, const float* __restrict__ h2,
    const float* __restrict__ ep, const float* __restrict__ bp2,
    const float* __restrict__ bp1,
    const float* __restrict__ kfF, const float* __restrict__ kfH,
    const float* __restrict__ lq, const float* __restrict__ lr,
    unsigned short* __restrict__ w0b, unsigned short* __restrict__ w1b,
    unsigned short* __restrict__ w2b, float* __restrict__ tW,
    float* __restrict__ kfK)
{
    int idx = blockIdx.x * blockDim.x + threadIdx.x;
    if (idx < 9216) {
        int d = idx;
        int sl = d & 7, sq = (d >> 3) & 3, co = (d >> 5) & 31;
        int r = d >> 10; int ky = r % 3, kt = r / 3;
        int q = sq ^ (co & 3) ^ ((co >> 2) & 3);
        float v = 0.f;
        if (q < 3 && sl < 3)
            v = cw0[((((size_t)co * 3 + sl) * 3 + kt) * 3 + ky) * 3 + q];
        w0b[d] = f2bf(v);
    } else if (idx < 64512) {
        int d = idx - 9216;
        int sl = d & 7, sg = (d >> 3) & 3, co = (d >> 5) & 63;
        int r = d >> 11; int k9 = r % 9, kt = r / 9;
        int ci = (sg ^ (co & 3)) * 8 + sl;
        w1b[d] = f2bf(cw1[((size_t)(co * 32 + ci) * 3 + kt) * 9 + k9]);
    } else if (idx < 230400) {
        int d = idx - 64512;
        int cip = d & 31; int rest = d >> 5;
        int co = rest % 96; rest /= 96;
        int k9 = rest % 9; int hh = rest / 9;
        int h = hh & 1, kt = hh >> 1;
        int ci = h * 32 + cip;
        w2b[d] = f2bf(cw2[((size_t)(co * 64 + ci) * 3 + kt) * 9 + k9]);
    } else if (idx < 730880) {
        int d = idx - 230400;
        const float* src; int N, K, base;
        if      (d < 262144) { src = ip;  N = 1024; K = 256; base = 0; }
        else if (d < 286720) { src = xp;  N = 48;   K = 512; base = 262144; }
        else if (d < 294912) { src = dt;  N = 512;  K = 16;  base = 286720; }
        else if (d < 425984) { src = op;  N = 256;  K = 512; base = 294912; }
        else if (d < 458752) { src = h1;  N = 128;  K = 256; base = 425984; }
        else if (d < 459264) { src = h2;  N = 4;    K = 128; base = 458752; }
        else if (d < 483840) { src = ep;  N = 256;  K = 96;  base = 459264; }
        else if (d < 500224) { src = bp2; N = 256;  K = 64;  base = 483840; }
        else                 { src = bp1; N = 64;   K = 4;   base = 500224; }
        int s = d - base;
        int o = s / K, k = s - o * K;
        tW[base + k * N + o] = src[s];
    } else {
        // KF gain block (blockIdx == gridDim-1). One wave; op order == old kf.
        if (threadIdx.x >= 64) return;
        int l16 = threadIdx.x & 15;
        int i = l16 >> 2, j = l16 & 3;
        int gb = threadIdx.x & 48;
        float Fv = kfF[l16], Hv = kfH[l16];
        float R4[4];
        #pragma unroll
        for (int k = 0; k < 4; ++k) R4[k] = expf(lr[k]) + 1e-6f;
        float qi = expf(lq[i]) + 1e-6f;
        float Pv = (i == j) ? 0.01f : 0.f;
        for (int t = 0; t < Tn; ++t) {
            float FPv = kf_mm(Fv, Pv, i, j, gb);
            float Ppv = kf_mmT(FPv, Fv, i, j, gb) + ((i == j) ? qi : 0.f);
            float HPv = kf_mm(Hv, Ppv, i, j, gb);
            float Sv = kf_mmT(HPv, Hv, i, j, gb) + ((i == j) ? R4[i] : 0.f);
            float Xv = Hv;
            #pragma unroll
            for (int c = 0; c < 4; ++c) {
                float piv = __shfl(Sv, gb + c * 5, 64);
                float dinv = 1.f / piv;
                if (i == c) { Sv *= dinv; Xv *= dinv; }
                float Scj = __shfl(Sv, gb + c * 4 + j, 64);
                float Xcj = __shfl(Xv, gb + c * 4 + j, 64);
                float f = __shfl(Sv, gb + i * 4 + c, 64);
                if (i != c) { Sv = fmaf(-f, Scj, Sv); Xv = fmaf(-f, Xcj, Xv); }
            }
            float Kv = kf_mmT(Ppv, Xv, i, j, gb);
            if (threadIdx.x < 16) kfK[t * 16 + l16] = Kv;
            float IKHv = ((i == j) ? 1.f : 0.f) - kf_mm(Kv, Hv, i, j, gb);
            float T1v = kf_mm(IKHv, Ppv, i, j, gb);
            float krk = 0.f;
            #pragma unroll
            for (int k = 0; k < 4; ++k)
                krk = fmaf(__shfl(Kv, gb + i * 4 + k, 64) * R4[k],
                           __shfl(Kv, gb + j * 4 + k, 64), krk);
            Pv = kf_mmT(T1v, IKHv, i, j, gb) + krk;
        }
    }
}

// ---------------------------------------------------------------------------
// Stage 0 as MFMA implicit GEMM, v3 (verified round 3, 326 baseline).
// ---------------------------------------------------------------------------
constexpr int C0_STR  = 68;
constexpr int C0_BLKS = 17 * C0_STR;

__global__ __launch_bounds__(512) void conv0_kernel(
    const float* __restrict__ in, const unsigned short* __restrict__ w0b,
    const float* __restrict__ bias, const float* __restrict__ gam,
    const float* __restrict__ bet, unsigned short* __restrict__ out)
{
    int tid  = threadIdx.x;
    int lane = tid & 63;
    int wv   = __builtin_amdgcn_readfirstlane(tid >> 6);
    int q    = lane >> 4;
    int l15  = lane & 15;
    int pyp  = wv >> 1;
    int hx   = wv & 1;
    int bI = blockIdx.x;
    int bt = bI >> 4, yt = (bI >> 1) & 7, xh = bI & 1;
    int b = bt >> 5, t = bt & 31;

    __shared__ __align__(16) unsigned short S[C0_BLKS * 8];
    __shared__ __align__(16) unsigned short W[9 * 32 * 32];

    f32x4 acc[2][2];
    #pragma unroll
    for (int dy = 0; dy < 2; ++dy)
        #pragma unroll
        for (int nt = 0; nt < 2; ++nt) acc[dy][nt] = (f32x4)0.f;

    {
        const uint4* wsrc = (const uint4*)w0b;
        uint4* wdst = (uint4*)W;
        for (int e = tid; e < 1152; e += 512) wdst[e] = wsrc[e];
    }

    int oxl = hx * 16 + l15;

    // hoisted fill descriptors (same for every stanza)
    int offs[3]; bool oksp[3];
    #pragma unroll
    for (int i = 0; i < 3; ++i) {
        int e = tid + 512 * i;
        int r = e / C0_STR, c = e - r * C0_STR;
        int gy = 16 * yt - 1 + r;
        int x  = 64 * xh + c - 1;
        bool act = (e < C0_BLKS);
        oksp[i] = act && gy >= 0 && gy < 128 && x >= 0 && x < 128;
        offs[i] = gy * 128 + x;
    }

    // hoisted epilogue params (co = nt*16 + l15)
    float biv[2] = {bias[l15], bias[l15 + 16]};
    float gv [2] = {gam [l15], gam [l15 + 16]};
    float bev[2] = {bet [l15], bet [l15 + 16]};

    float pf[3][3];
    auto ldG = [&](int ts) {
        bool tok = ((unsigned)ts < (unsigned)Tn);
        const float* base = in + (size_t)(b * Tn + (tok ? ts : 0)) * 49152;
        #pragma unroll
        for (int i = 0; i < 3; ++i) {
            bool ok = tok && oksp[i];
            const float* p = base + offs[i];
            pf[i][0] = ok ? p[0]     : 0.f;
            pf[i][1] = ok ? p[16384] : 0.f;
            pf[i][2] = ok ? p[32768] : 0.f;
        }
    };
    auto stS = [&]() {
        #pragma unroll
        for (int i = 0; i < 3; ++i) {
            if (i < 2 || tid < C0_BLKS - 1024) {
                unsigned w0_, w1_;
                asm("v_cvt_pk_bf16_f32 %0, %1, %2" : "=v"(w0_) : "v"(pf[i][0]), "v"(pf[i][1]));
                asm("v_cvt_pk_bf16_f32 %0, %1, %2" : "=v"(w1_) : "v"(pf[i][2]), "v"(0.f));
                uint4 pk; pk.x = w0_; pk.y = w1_; pk.z = 0u; pk.w = 0u;
                *(uint4*)(S + (size_t)(tid + 512 * i) * 8) = pk;
            }
        }
    };
    auto compute = [&](int kt) {
        #pragma unroll
        for (int ky = 0; ky < 3; ++ky) {
            short8 bfr[2];
            #pragma unroll
            for (int nt = 0; nt < 2; ++nt) {
                int co = nt * 16 + l15;
                int i16 = ((kt * 3 + ky) * 32 + co) * 4 +
                          (q ^ (co & 3) ^ ((co >> 2) & 3));
                bfr[nt] = *(const short8*)(W + (size_t)i16 * 8);
            }
            #pragma unroll
            for (int dy = 0; dy < 2; ++dy) {
                int r = 4 * pyp + 2 * dy + ky;
                short8 af = (short8)0;
                if (q < 3)
                    af = *(const short8*)(S + (size_t)(r * C0_STR + 2 * oxl + q) * 8);
                #pragma unroll
                for (int nt = 0; nt < 2; ++nt)
                    acc[dy][nt] = __builtin_amdgcn_mfma_f32_16x16x32_bf16(
                        af, bfr[nt], acc[dy][nt], 0, 0, 0);
            }
        }
    };

    // software pipeline: loads for stanza k+1 in flight during compute k
    ldG(t - 1);
    stS();
    ldG(t);
    __syncthreads();
    compute(0);
    __syncthreads();
    stS();
    ldG(t + 1);
    __syncthreads();
    compute(1);
    __syncthreads();
    stS();
    __syncthreads();
    compute(2);

    unsigned short* dst = out + (size_t)bt * 32768;
    #pragma unroll
    for (int nt = 0; nt < 2; ++nt) {
        int co = nt * 16 + l15;
        float bi = biv[nt], g = gv[nt], be = bev[nt];
        #pragma unroll
        for (int j = 0; j < 2; ++j) {
            float m0 = fmaxf(fmaf(g, acc[0][nt][2 * j]     + bi, be), 0.f);
            float m1 = fmaxf(fmaf(g, acc[0][nt][2 * j + 1] + bi, be), 0.f);
            float m2 = fmaxf(fmaf(g, acc[1][nt][2 * j]     + bi, be), 0.f);
            float m3 = fmaxf(fmaf(g, acc[1][nt][2 * j + 1] + bi, be), 0.f);
            float p = fmaxf(fmaxf(m0, m1), fmaxf(m2, m3));
            int pox = xh * 16 + hx * 8 + q * 2 + j;
            int poy = yt * 4 + pyp;
            dst[(poy * 32 + pox) * 32 + co] = f2bf(p);
        }
    }
}

// ---------------------------------------------------------------------------
// Stage 1 as MFMA implicit GEMM, y-half split (verified round 9).
// ---------------------------------------------------------------------------
__global__ __launch_bounds__(512) void conv1_kernel(
    const unsigned short* __restrict__ in, const unsigned short* __restrict__ w1b,
    const float* __restrict__ bias, const float* __restrict__ gam,
    const float* __restrict__ bet, unsigned short* __restrict__ out)
{
    int tid  = threadIdx.x;
    int lane = tid & 63;
    int wv   = tid >> 6;
    int q    = lane >> 4;
    int l15  = lane & 15;
    int oyp  = wv >> 1;
    int nh   = wv & 1;
    int bt = blockIdx.x >> 1, half = blockIdx.x & 1;
    int b = bt >> 5, t = bt & 31;

    __shared__ __align__(16) unsigned short S[17 * 34 * 32];
    __shared__ __align__(16) unsigned short W[9 * 64 * 32];

    f32x4 acc[2][2];
    #pragma unroll
    for (int mt = 0; mt < 2; ++mt)
        #pragma unroll
        for (int nt = 0; nt < 2; ++nt) acc[mt][nt] = (f32x4)0.f;

    for (int kt = 0; kt < 3; ++kt) {
        int ts = t + kt - 1;
        if (ts < 0 || ts >= Tn) continue;
        __syncthreads();
        const unsigned short* src = in + (size_t)(b * Tn + ts) * 32768;
        for (int e = tid; e < 17 * 34 * 4; e += 512) {
            int sb = e & 3;
            int pos = e >> 2;
            int ys = pos / 34, xs = pos - ys * 34;
            int g = sb ^ ((xs >> 1) & 3);
            int y = 16 * half + ys - 1, x = xs - 1;
            ushort8 v = (ushort8)0;
            if (y >= 0 && x >= 0 && x < 32)
                v = *(const ushort8*)(src + ((y * 32 + x) * 32 + g * 8));
            *(ushort8*)(S + (size_t)e * 8) = v;
        }
        {
            const uint4* wsrc = (const uint4*)(w1b + kt * 18432);
            uint4* wdst = (uint4*)W;
            for (int e = tid; e < 2304; e += 512) wdst[e] = wsrc[e];
        }
        __syncthreads();

        for (int k9 = 0; k9 < 9; ++k9) {
            int ky = k9 / 3, kx = k9 - ky * 3;
            short8 bf[2];
            #pragma unroll
            for (int nt = 0; nt < 2; ++nt) {
                int co = nh * 32 + nt * 16 + l15;
                int blk = (k9 * 64 + co) * 4 + (q ^ (co & 3));
                bf[nt] = *(const short8*)(W + blk * 8);
            }
            short8 af[2];
            #pragma unroll
            for (int mt = 0; mt < 2; ++mt) {
                int oyl = 2 * oyp + mt;
                int ys = 2 * oyl + ky;
                int xs = 2 * l15 + kx;
                int blk = (ys * 34 + xs) * 4 + (q ^ ((xs >> 1) & 3));
                af[mt] = *(const short8*)(S + blk * 8);
            }
            #pragma unroll
            for (int mt = 0; mt < 2; ++mt)
                #pragma unroll
                for (int nt = 0; nt < 2; ++nt)
                    acc[mt][nt] = __builtin_amdgcn_mfma_f32_16x16x32_bf16(
                        af[mt], bf[nt], acc[mt][nt], 0, 0, 0);
        }
    }

    unsigned short* dst = out + (size_t)bt * 4096;
    #pragma unroll
    for (int nt = 0; nt < 2; ++nt) {
        int co = nh * 32 + nt * 16 + l15;
        float bi = bias[co], g = gam[co], be = bet[co];
        #pragma unroll
        for (int j = 0; j < 2; ++j) {
            float m0 = fmaxf(fmaf(g, acc[0][nt][2 * j]     + bi, be), 0.f);
            float m1 = fmaxf(fmaf(g, acc[0][nt][2 * j + 1] + bi, be), 0.f);
            float m2 = fmaxf(fmaf(g, acc[1][nt][2 * j]     + bi, be), 0.f);
            float m3 = fmaxf(fmaf(g, acc[1][nt][2 * j + 1] + bi, be), 0.f);
            float p = fmaxf(fmaxf(m0, m1), fmaxf(m2, m3));
            int px = 2 * q + j, py = half * 4 + oyp;
            dst[(py * 8 + px) * 64 + co] = f2bf(p);
        }
    }
}

// ---------------------------------------------------------------------------
// Stage 2 as MFMA implicit GEMM (verified round 8).
// ---------------------------------------------------------------------------
__global__ __launch_bounds__(384) void conv2_kernel(
    const unsigned short* __restrict__ in, const unsigned short* __restrict__ w2b,
    const float* __restrict__ bias, const float* __restrict__ gam,
    const float* __restrict__ bet, float* __restrict__ out)
{
    int tid  = threadIdx.x;
    int lane = tid & 63;
    int wv   = tid >> 6;
    int q    = lane >> 4;
    int l15  = lane & 15;
    int bt = blockIdx.x;
    int b = bt >> 5, t = bt & 31;

    __shared__ __align__(16) unsigned short W[864 * 5 * 8];
    __shared__ __align__(16) unsigned short S[81 * 5 * 8];

    f32x4 acc = (f32x4)0.f;

    for (int kt = 0; kt < 3; ++kt) {
        int ts = t + kt - 1;
        if (ts < 0 || ts >= Tn) continue;
        for (int h = 0; h < 2; ++h) {
            __syncthreads();
            const unsigned short* wsrc = w2b + (size_t)((kt * 2 + h) * 9) * 96 * 32;
            for (int e = tid; e < 3456; e += 384) {
                int r = e >> 2, qq = e & 3;
                uint4 v = *(const uint4*)(wsrc + r * 32 + qq * 8);
                *(uint4*)(W + (r * 5 + qq) * 8) = v;
            }
            const unsigned short* src = in + (size_t)(b * Tn + ts) * 4096 + h * 32;
            for (int e = tid; e < 81 * 4; e += 384) {
                int cb = e & 3, p = e >> 2;
                int ys = p / 9, xs = p - ys * 9;
                int y = ys - 1, x = xs - 1;
                ushort8 v = (ushort8)0;
                if (y >= 0 && x >= 0 && y < 8 && x < 8)
                    v = *(const ushort8*)(src + ((y * 8 + x) * 64 + cb * 8));
                *(ushort8*)(S + (size_t)(p * 5 + cb) * 8) = v;
            }
            __syncthreads();

            int oy = l15 >> 2, ox = l15 & 3;
            #pragma unroll
            for (int k9 = 0; k9 < 9; ++k9) {
                int ky = k9 / 3, kx = k9 - ky * 3;
                short8 bf = *(const short8*)(W + (size_t)((k9 * 96 + wv * 16 + l15) * 5 + q) * 8);
                int p = (2 * oy + ky) * 9 + (2 * ox + kx);
                short8 af = *(const short8*)(S + (size_t)(p * 5 + q) * 8);
                acc = __builtin_amdgcn_mfma_f32_16x16x32_bf16(af, bf, acc, 0, 0, 0);
            }
        }
    }

    int co = wv * 16 + l15;
    float bi = bias[co], g = gam[co], be = bet[co];
    float v0 = fmaxf(fmaf(g, acc[0] + bi, be), 0.f);
    float v1 = fmaxf(fmaf(g, acc[1] + bi, be), 0.f);
    float v2 = fmaxf(fmaf(g, acc[2] + bi, be), 0.f);
    float v3 = fmaxf(fmaf(g, acc[3] + bi, be), 0.f);
    float p0 = fmaxf(v0, v1);
    float p1 = fmaxf(v2, v3);
    float r0 = fmaxf(p0, __shfl_xor(p0, 16));
    float r1 = fmaxf(p1, __shfl_xor(p1, 16));
    if ((q & 1) == 0) {
        int py = q >> 1;
        float* o = out + (size_t)(bt * 96 + co) * 4 + py * 2;
        o[0] = r0;
        o[1] = r1;
    }
}

// ---------------------------------------------------------------------------
// FUSED TAIL (cooperative): u -> in_proj -> conv1d/x_proj/dt -> ssm ->
// out_head -> kf, with grid.sync() between cross-block phases.
// Grid 256 x 512. Phase bodies == verified round-3/5 kernels (bit-identical
// per-output chains). u lives in LDS only (no global round trip).
// ---------------------------------------------------------------------------
__global__ __launch_bounds__(512) void tail_fused(
    const float* __restrict__ buf2, const float* __restrict__ epT,
    const float* __restrict__ ep_b, const float* __restrict__ bb,
    const float* __restrict__ bp1T, const float* __restrict__ bp1_b,
    const float* __restrict__ bp2T, const float* __restrict__ bp2_b,
    const float* __restrict__ ipwT, float* __restrict__ xzb,
    const float* __restrict__ c1w, const float* __restrict__ c1b,
    const float* __restrict__ xpw, const float* __restrict__ dtwT,
    const float* __restrict__ dt_b,
    float* __restrict__ xsb, float* __restrict__ xdb, float* __restrict__ dtbf,
    const float* __restrict__ A_log, const float* __restrict__ Dp,
    float* __restrict__ yb,
    const float* __restrict__ opwT, const float* __restrict__ h1wT,
    const float* __restrict__ h1_b, const float* __restrict__ h2w,
    const float* __restrict__ h2_b, float* __restrict__ meas_out,
    const float* __restrict__ Fin, const float* __restrict__ Hmin,
    const float* __restrict__ kfK, float* __restrict__ pred)
{
    cg::grid_group grid = cg::this_grid();
    int bt  = blockIdx.x;
    int b   = bt >> 5, t = bt & 31;
    int tid = threadIdx.x;

    __shared__ float hs[64];
    __shared__ float gap[96];
    __shared__ float u_lds[256];
    __shared__ float xs_lds[512];
    __shared__ float xd_lds[48];
    __shared__ float y_lds[512];
    __shared__ float mo_lds[256];
    __shared__ float hid_lds[128];

    // ---- Phase A: u (LDS) + in_proj -> xzb ----
    if (tid < 64) {
        float a = bp1_b[tid];
        #pragma unroll
        for (int k = 0; k < 4; ++k) a = fmaf(bp1T[k * 64 + tid], bb[bt * 4 + k], a);
        hs[tid] = fmaxf(a, 0.f);
    } else if (tid < 160) {
        int c = tid - 64;
        const float* p = buf2 + ((size_t)bt * 96 + c) * 4;
        gap[c] = 0.25f * (p[0] + p[1] + p[2] + p[3]);
    }
    __syncthreads();
    if (tid < 256) {
        float ff = ep_b[tid];
        for (int c = 0; c < 96; ++c) ff = fmaf(gap[c], epT[c * 256 + tid], ff);
        float bfv = bp2_b[tid];
        for (int j = 0; j < 64; ++j) bfv = fmaf(hs[j], bp2T[j * 256 + tid], bfv);
        u_lds[tid] = ff + bfv;
    }
    __syncthreads();
    {
        // in_proj: 512 threads x 2 outputs (per-output ascending-k chain ==
        // previous float4 version -> bit-identical).
        const float2* wbase = (const float2*)ipwT + tid;   // + k*512 per row
        float2 acc = {0.f, 0.f};
        #pragma unroll 8
        for (int k = 0; k < 256; ++k) {
            float uk = u_lds[k];
            float2 w2 = wbase[(size_t)k * 512];
            acc.x = fmaf(uk, w2.x, acc.x);
            acc.y = fmaf(uk, w2.y, acc.y);
        }
        *(float2*)(xzb + (size_t)bt * 1024 + 2 * tid) = acc;
    }

    grid.sync();

    // ---- Phase B: conv1d+silu -> x_proj -> dt_proj (verbatim convxd) ----
    {
        float acc = c1b[tid];
        #pragma unroll
        for (int k = 0; k < 4; ++k) {
            int ts = t - 3 + k;
            if (ts >= 0)
                acc = fmaf(c1w[tid * 4 + k], xzb[(size_t)(b * Tn + ts) * 1024 + tid], acc);
        }
        float v = acc / (1.f + expf(-acc));
        xs_lds[tid] = v;
        xsb[(size_t)bt * 512 + tid] = v;
    }
    __syncthreads();
    {
        int wv = tid >> 6, ln = tid & 63;
        #pragma unroll
        for (int u = 0; u < 6; ++u) {
            int o = wv * 6 + u;
            const float* wrow = xpw + (size_t)o * 512;
            float acc = 0.f;
            #pragma unroll
            for (int e = 0; e < 8; ++e)
                acc = fmaf(wrow[ln + 64 * e], xs_lds[ln + 64 * e], acc);
            acc += __shfl_xor(acc, 32); acc += __shfl_xor(acc, 16);
            acc += __shfl_xor(acc, 8);  acc += __shfl_xor(acc, 4);
            acc += __shfl_xor(acc, 2);  acc += __shfl_xor(acc, 1);
            if (ln == 0) {
                xd_lds[o] = acc;
                xdb[(size_t)bt * 48 + o] = acc;
            }
        }
    }
    __syncthreads();
    {
        float a = dt_b[tid];
        #pragma unroll
        for (int k = 0; k < 16; ++k) a = fmaf(xd_lds[k], dtwT[k * 512 + tid], a);
        a = (a > 20.f) ? a : log1pf(expf(a));
        dtbf[(size_t)bt * 512 + tid] = a;
    }

    grid.sync();

    // ---- Phase C: selective scan (waves 0-3; same gid map as before) ----
    if (tid < 256) {
        int lane = tid & 63;
        int s = lane & 15, dsub = lane >> 4;
        int gid = bt * 4 + (tid >> 6);
        int sb = gid >> 7;
        int d = ((gid & 127) << 2) + dsub;

        float A = -expf(A_log[d * 16 + s]);
        float Dv = Dp[d];
        float h = 0.f;
        for (int tt = 0; tt < Tn; ++tt) {
            int bidx = sb * Tn + tt;
            float dtv = dtbf[(size_t)bidx * 512 + d];
            float xv  = xsb [(size_t)bidx * 512 + d];
            float Bs  = xdb[(size_t)bidx * 48 + 16 + s];
            float Cs  = xdb[(size_t)bidx * 48 + 32 + s];
            float dA = expf(dtv * A);
            h = fmaf(dA, h, dtv * Bs * xv);
            float c = h * Cs;
            c += __shfl_xor(c, 8, 16);
            c += __shfl_xor(c, 4, 16);
            c += __shfl_xor(c, 2, 16);
            c += __shfl_xor(c, 1, 16);
            if (s == 0) {
                float zv = xzb[(size_t)bidx * 1024 + 512 + d];
                float sig = 1.f / (1.f + expf(-zv));
                yb[(size_t)bidx * 512 + d] = (c + Dv * xv) * (zv * sig);
            }
        }
    }

    grid.sync();

    // ---- Phase D: out_proj -> h1 -> h2 -> meas (verbatim, guarded) ----
    if (tid < 256) {
        y_lds[tid]       = yb[(size_t)bt * 512 + tid];
        y_lds[tid + 256] = yb[(size_t)bt * 512 + tid + 256];
    }
    __syncthreads();
    if (tid < 256) {
        float a = 0.f;
        for (int k = 0; k < 512; ++k) a = fmaf(y_lds[k], opwT[k * 256 + tid], a);
        mo_lds[tid] = a;
    }
    __syncthreads();
    if (tid < 128) {
        float a = h1_b[tid];
        for (int k = 0; k < 256; ++k) a = fmaf(mo_lds[k], h1wT[k * 128 + tid], a);
        hid_lds[tid] = fmaxf(a, 0.f);
    }
    __syncthreads();
    if (tid < 64) {
        int o2 = tid >> 4, l15 = tid & 15;
        float acc = 0.f;
        #pragma unroll
        for (int e = 0; e < 8; ++e)
            acc = fmaf(h2w[o2 * 128 + l15 + 16 * e], hid_lds[l15 + 16 * e], acc);
        acc += __shfl_xor(acc, 8, 16);
        acc += __shfl_xor(acc, 4, 16);
        acc += __shfl_xor(acc, 2, 16);
        acc += __shfl_xor(acc, 1, 16);
        if (l15 == 0) {
            float a = acc + h2_b[o2];
            meas_out[bt * 4 + o2] = 1.f / (1.f + expf(-a));
        }
    }

    grid.sync();

    // ---- Phase E: Kalman state recurrence (block 0 only) ----
    if (bt == 0 && tid < 128) {
        int kb  = tid >> 4;
        int l16 = tid & 15;
        int i = l16 >> 2, j = l16 & 3;
        int gb = tid & 48;

        float Fv = Fin[l16], Hv = Hmin[l16];
        float sv = bb[kb * 128 + j];

        for (int tt = 0; tt < Tn; ++tt) {
            float mv = meas_out[(kb * Tn + tt) * 4 + j];
            float Kv = kfK[tt * 16 + l16];
            float tr = Fv * sv;
            tr += __shfl_xor(tr, 1); tr += __shfl_xor(tr, 2);
            float spv = tr;
            float spj = __shfl(spv, gb + j * 4, 64);
            float hsp = Hv * spj;
            hsp += __shfl_xor(hsp, 1); hsp += __shfl_xor(hsp, 2);
            float yrv = mv - __shfl(hsp, gb + j * 4, 64);
            float t3 = Kv * yrv;
            t3 += __shfl_xor(t3, 1); t3 += __shfl_xor(t3, 2);
            float snv = spv + t3;
            if (j == 0) pred[(kb * Tn + tt) * 4 + i] = snv;
            sv = __shfl(snv, gb + j * 4, 64);
        }
    }
}

// ---------------------------------------------------------------------------
extern "C" void kernel_launch(void* const* d_in, const int* in_sizes, int n_in,
                              void* d_out, int out_size, void* d_ws, size_t ws_size,
                              hipStream_t stream)
{
    const float* frames = (const float*)d_in[0];
    const float* bb     = (const float*)d_in[1];
    const float* cw0 = (const float*)d_in[2],  *cb0 = (const float*)d_in[3];
    const float* g0  = (const float*)d_in[4],  *be0 = (const float*)d_in[5];
    const float* cw1 = (const float*)d_in[6],  *cb1 = (const float*)d_in[7];
    const float* g1  = (const float*)d_in[8],  *be1 = (const float*)d_in[9];
    const float* cw2 = (const float*)d_in[10], *cb2 = (const float*)d_in[11];
    const float* g2  = (const float*)d_in[12], *be2 = (const float*)d_in[13];
    const float* ep_w  = (const float*)d_in[14], *ep_b  = (const float*)d_in[15];
    const float* bp1_w = (const float*)d_in[16], *bp1_b = (const float*)d_in[17];
    const float* bp2_w = (const float*)d_in[18], *bp2_b = (const float*)d_in[19];
    const float* in_proj_w = (const float*)d_in[20];
    const float* c1w = (const float*)d_in[21], *c1b = (const float*)d_in[22];
    const float* x_proj_w = (const float*)d_in[23];
    const float* dt_w = (const float*)d_in[24], *dt_b = (const float*)d_in[25];
    const float* A_log = (const float*)d_in[26], *Dp = (const float*)d_in[27];
    const float* out_proj_w = (const float*)d_in[28];
    const float* h1_w = (const float*)d_in[29], *h1_b = (const float*)d_in[30];
    const float* h2_w = (const float*)d_in[31], *h2_b = (const float*)d_in[32];
    const float* kfF = (const float*)d_in[33], *kfH = (const float*)d_in[34];
    const float* kfq = (const float*)d_in[35], *kfr = (const float*)d_in[36];

    // workspace layout
    float* ws   = (float*)d_ws;
    float* buf2 = ws;                        // (256,96,2,2)   98304
    float* xzb  = buf2 + 98304;              // (256,1024)    262144
    float* xsb  = xzb  + 262144;             // (256,512)     131072
    float* xdb  = xsb  + 131072;             // (256,48)       12288
    float* dtbf = xdb  + 12288;              // (256,512)     131072
    float* yb   = dtbf + 131072;             // (256,512)     131072
    float* tW   = yb   + 131072;             // transposed weights 500480
    float* kfK  = tW + 500480;               // (32,16) KF gains      512
    unsigned short* buf0b = (unsigned short*)(kfK + 512);    // bf16 (256,32,32,32)
    unsigned short* buf1b = buf0b + 8388608;                 // bf16 (256,8,8,64)
    unsigned short* w2b   = buf1b + 131072;
    unsigned short* w1b   = w2b + 165888;
    unsigned short* w0b   = w1b + 55296;

    float* ipwT = tW;
    float* dtwT = tW + 286720;
    float* opwT = tW + 294912;
    float* h1wT = tW + 425984;
    float* epwT = tW + 459264;
    float* bp2T = tW + 483840;
    float* bp1T = tW + 500224;

    float* kf_out   = (float*)d_out;          // (8,32,4)
    float* meas_out = kf_out + Bn * Tn * 4;   // (8,32,4)

    // 730880/256 = 2855 copy blocks + 1 KF-gain block
    prep_all<<<dim3(2856), 256, 0, stream>>>(cw0, cw1, cw2,
                                             in_proj_w, x_proj_w, dt_w, out_proj_w,
                                             h1_w, h2_w, ep_w, bp2_w, bp1_w,
                                             kfF, kfH, kfq, kfr,
                                             w0b, w1b, w2b, tW, kfK);

    conv0_kernel<<<dim3(4096), 512, 0, stream>>>(frames, w0b, cb0, g0, be0, buf0b);
    conv1_kernel<<<dim3(512), 512, 0, stream>>>(buf0b, w1b, cb1, g1, be1, buf1b);
    conv2_kernel<<<dim3(256), 384, 0, stream>>>(buf1b, w2b, cb2, g2, be2, buf2);

    void* args[] = {
        (void*)&buf2, (void*)&epwT, (void*)&ep_b, (void*)&bb,
        (void*)&bp1T, (void*)&bp1_b, (void*)&bp2T, (void*)&bp2_b,
        (void*)&ipwT, (void*)&xzb,
        (void*)&c1w, (void*)&c1b, (void*)&x_proj_w, (void*)&dtwT, (void*)&dt_b,
        (void*)&xsb, (void*)&xdb, (void*)&dtbf,
        (void*)&A_log, (void*)&Dp, (void*)&yb,
        (void*)&opwT, (void*)&h1wT, (void*)&h1_b, (void*)&h2_w, (void*)&h2_b,
        (void*)&meas_out,
        (void*)&kfF, (void*)&kfH, (void*)&kfK, (void*)&kf_out
    };
    hipError_t err = hipLaunchCooperativeKernel((const void*)tail_fused,
                                                dim3(256), dim3(512),
                                                args, 0, stream);
    (void)err;
}

// Round 8
// 322.474 us; speedup vs baseline: 1.4907x; 1.4907x over previous
//
#include <hip/hip_runtime.h>
#include <math.h>

// Problem constants
constexpr int Bn = 8, Tn = 32;
constexpr int D_INNER = 512;

typedef __attribute__((ext_vector_type(8))) short short8;   // 8 bf16
typedef __attribute__((ext_vector_type(8))) unsigned short ushort8;
typedef __attribute__((ext_vector_type(4))) float f32x4;

__device__ inline unsigned short f2bf(float x) {
    unsigned int u = __float_as_uint(x);
    unsigned int r = (u + 0x7FFF + ((u >> 16) & 1)) >> 16;  // RNE
    return (unsigned short)r;
}

// 4x4 matrix helpers on 16-lane groups (lane = i*4+j within group)
__device__ __forceinline__ float kf_mm(float Av, float Bv, int i, int j, int gb) {
    float c = 0.f;
    #pragma unroll
    for (int k = 0; k < 4; ++k)
        c = fmaf(__shfl(Av, gb + i * 4 + k, 64), __shfl(Bv, gb + k * 4 + j, 64), c);
    return c;
}
__device__ __forceinline__ float kf_mmT(float Av, float Bv, int i, int j, int gb) {
    float c = 0.f;
    #pragma unroll
    for (int k = 0; k < 4; ++k)
        c = fmaf(__shfl(Av, gb + i * 4 + k, 64), __shfl(Bv, gb + j * 4 + k, 64), c);
    return c;
}

// ---------------------------------------------------------------------------
// ONE prep kernel: conv bf16 weight packs + tail-weight transposes (now with
// compile-time-constant divisors per matrix) + KF gain sequence (extra block).
// ---------------------------------------------------------------------------
__global__ void prep_all(
    const float* __restrict__ cw0, const float* __restrict__ cw1,
    const float* __restrict__ cw2,
    const float* __restrict__ ip, const float* __restrict__ xp,
    const float* __restrict__ dt, const float* __restrict__ op,
    const float* __restrict__ h1, const float* __restrict__ h2,
    const float* __restrict__ ep, const float* __restrict__ bp2,
    const float* __restrict__ bp1,
    const float* __restrict__ kfF, const float* __restrict__ kfH,
    const float* __restrict__ lq, const float* __restrict__ lr,
    unsigned short* __restrict__ w0b, unsigned short* __restrict__ w1b,
    unsigned short* __restrict__ w2b, float* __restrict__ tW,
    float* __restrict__ kfK)
{
    int idx = blockIdx.x * blockDim.x + threadIdx.x;
    if (idx < 9216) {
        int d = idx;
        int sl = d & 7, sq = (d >> 3) & 3, co = (d >> 5) & 31;
        int r = d >> 10; int ky = r % 3, kt = r / 3;
        int q = sq ^ (co & 3) ^ ((co >> 2) & 3);
        float v = 0.f;
        if (q < 3 && sl < 3)
            v = cw0[((((size_t)co * 3 + sl) * 3 + kt) * 3 + ky) * 3 + q];
        w0b[d] = f2bf(v);
    } else if (idx < 64512) {
        int d = idx - 9216;
        int sl = d & 7, sg = (d >> 3) & 3, co = (d >> 5) & 63;
        int r = d >> 11; int k9 = r % 9, kt = r / 9;
        int ci = (sg ^ (co & 3)) * 8 + sl;
        w1b[d] = f2bf(cw1[((size_t)(co * 32 + ci) * 3 + kt) * 9 + k9]);
    } else if (idx < 230400) {
        int d = idx - 64512;
        int cip = d & 31; int rest = d >> 5;
        int co = rest % 96; rest /= 96;
        int k9 = rest % 9; int hh = rest / 9;
        int h = hh & 1, kt = hh >> 1;
        int ci = h * 32 + cip;
        w2b[d] = f2bf(cw2[((size_t)(co * 64 + ci) * 3 + kt) * 9 + k9]);
    } else if (idx < 730880) {
        int d = idx - 230400;
        // transposes with compile-time K (shift / magic-mul instead of
        // runtime division)
        if (d < 262144)      { int o = d >> 8, k = d & 255;
                               tW[k * 1024 + o] = ip[d]; }
        else if (d < 286720) { int s = d - 262144; int o = s >> 9, k = s & 511;
                               tW[262144 + k * 48 + o] = xp[s]; }
        else if (d < 294912) { int s = d - 286720; int o = s >> 4, k = s & 15;
                               tW[286720 + k * 512 + o] = dt[s]; }
        else if (d < 425984) { int s = d - 294912; int o = s >> 9, k = s & 511;
                               tW[294912 + k * 256 + o] = op[s]; }
        else if (d < 458752) { int s = d - 425984; int o = s >> 8, k = s & 255;
                               tW[425984 + k * 128 + o] = h1[s]; }
        else if (d < 459264) { int s = d - 458752; int o = s >> 7, k = s & 127;
                               tW[458752 + k * 4 + o] = h2[s]; }
        else if (d < 483840) { int s = d - 459264; int o = s / 96, k = s - o * 96;
                               tW[459264 + k * 256 + o] = ep[s]; }
        else if (d < 500224) { int s = d - 483840; int o = s >> 6, k = s & 63;
                               tW[483840 + k * 256 + o] = bp2[s]; }
        else                 { int s = d - 500224; int o = s >> 2, k = s & 3;
                               tW[500224 + k * 64 + o] = bp1[s]; }
    } else {
        // KF gain block (blockIdx == gridDim-1). One wave; op order == old kf.
        if (threadIdx.x >= 64) return;
        int l16 = threadIdx.x & 15;
        int i = l16 >> 2, j = l16 & 3;
        int gb = threadIdx.x & 48;
        float Fv = kfF[l16], Hv = kfH[l16];
        float R4[4];
        #pragma unroll
        for (int k = 0; k < 4; ++k) R4[k] = expf(lr[k]) + 1e-6f;
        float qi = expf(lq[i]) + 1e-6f;
        float Pv = (i == j) ? 0.01f : 0.f;
        for (int t = 0; t < Tn; ++t) {
            float FPv = kf_mm(Fv, Pv, i, j, gb);
            float Ppv = kf_mmT(FPv, Fv, i, j, gb) + ((i == j) ? qi : 0.f);
            float HPv = kf_mm(Hv, Ppv, i, j, gb);
            float Sv = kf_mmT(HPv, Hv, i, j, gb) + ((i == j) ? R4[i] : 0.f);
            float Xv = Hv;
            #pragma unroll
            for (int c = 0; c < 4; ++c) {
                float piv = __shfl(Sv, gb + c * 5, 64);
                float dinv = 1.f / piv;
                if (i == c) { Sv *= dinv; Xv *= dinv; }
                float Scj = __shfl(Sv, gb + c * 4 + j, 64);
                float Xcj = __shfl(Xv, gb + c * 4 + j, 64);
                float f = __shfl(Sv, gb + i * 4 + c, 64);
                if (i != c) { Sv = fmaf(-f, Scj, Sv); Xv = fmaf(-f, Xcj, Xv); }
            }
            float Kv = kf_mmT(Ppv, Xv, i, j, gb);
            if (threadIdx.x < 16) kfK[t * 16 + l16] = Kv;
            float IKHv = ((i == j) ? 1.f : 0.f) - kf_mm(Kv, Hv, i, j, gb);
            float T1v = kf_mm(IKHv, Ppv, i, j, gb);
            float krk = 0.f;
            #pragma unroll
            for (int k = 0; k < 4; ++k)
                krk = fmaf(__shfl(Kv, gb + i * 4 + k, 64) * R4[k],
                           __shfl(Kv, gb + j * 4 + k, 64), krk);
            Pv = kf_mmT(T1v, IKHv, i, j, gb) + krk;
        }
    }
}

// ---------------------------------------------------------------------------
// Stage 0 as MFMA implicit GEMM, v3 (verified round 3, 326 baseline).
// ---------------------------------------------------------------------------
constexpr int C0_STR  = 68;
constexpr int C0_BLKS = 17 * C0_STR;

__global__ __launch_bounds__(512) void conv0_kernel(
    const float* __restrict__ in, const unsigned short* __restrict__ w0b,
    const float* __restrict__ bias, const float* __restrict__ gam,
    const float* __restrict__ bet, unsigned short* __restrict__ out)
{
    int tid  = threadIdx.x;
    int lane = tid & 63;
    int wv   = __builtin_amdgcn_readfirstlane(tid >> 6);
    int q    = lane >> 4;
    int l15  = lane & 15;
    int pyp  = wv >> 1;
    int hx   = wv & 1;
    int bI = blockIdx.x;
    int bt = bI >> 4, yt = (bI >> 1) & 7, xh = bI & 1;
    int b = bt >> 5, t = bt & 31;

    __shared__ __align__(16) unsigned short S[C0_BLKS * 8];
    __shared__ __align__(16) unsigned short W[9 * 32 * 32];

    f32x4 acc[2][2];
    #pragma unroll
    for (int dy = 0; dy < 2; ++dy)
        #pragma unroll
        for (int nt = 0; nt < 2; ++nt) acc[dy][nt] = (f32x4)0.f;

    {
        const uint4* wsrc = (const uint4*)w0b;
        uint4* wdst = (uint4*)W;
        for (int e = tid; e < 1152; e += 512) wdst[e] = wsrc[e];
    }

    int oxl = hx * 16 + l15;

    // hoisted fill descriptors (same for every stanza)
    int offs[3]; bool oksp[3];
    #pragma unroll
    for (int i = 0; i < 3; ++i) {
        int e = tid + 512 * i;
        int r = e / C0_STR, c = e - r * C0_STR;
        int gy = 16 * yt - 1 + r;
        int x  = 64 * xh + c - 1;
        bool act = (e < C0_BLKS);
        oksp[i] = act && gy >= 0 && gy < 128 && x >= 0 && x < 128;
        offs[i] = gy * 128 + x;
    }

    // hoisted epilogue params (co = nt*16 + l15)
    float biv[2] = {bias[l15], bias[l15 + 16]};
    float gv [2] = {gam [l15], gam [l15 + 16]};
    float bev[2] = {bet [l15], bet [l15 + 16]};

    float pf[3][3];
    auto ldG = [&](int ts) {
        bool tok = ((unsigned)ts < (unsigned)Tn);
        const float* base = in + (size_t)(b * Tn + (tok ? ts : 0)) * 49152;
        #pragma unroll
        for (int i = 0; i < 3; ++i) {
            bool ok = tok && oksp[i];
            const float* p = base + offs[i];
            pf[i][0] = ok ? p[0]     : 0.f;
            pf[i][1] = ok ? p[16384] : 0.f;
            pf[i][2] = ok ? p[32768] : 0.f;
        }
    };
    auto stS = [&]() {
        #pragma unroll
        for (int i = 0; i < 3; ++i) {
            if (i < 2 || tid < C0_BLKS - 1024) {
                unsigned w0_, w1_;
                asm("v_cvt_pk_bf16_f32 %0, %1, %2" : "=v"(w0_) : "v"(pf[i][0]), "v"(pf[i][1]));
                asm("v_cvt_pk_bf16_f32 %0, %1, %2" : "=v"(w1_) : "v"(pf[i][2]), "v"(0.f));
                uint4 pk; pk.x = w0_; pk.y = w1_; pk.z = 0u; pk.w = 0u;
                *(uint4*)(S + (size_t)(tid + 512 * i) * 8) = pk;
            }
        }
    };
    auto compute = [&](int kt) {
        #pragma unroll
        for (int ky = 0; ky < 3; ++ky) {
            short8 bfr[2];
            #pragma unroll
            for (int nt = 0; nt < 2; ++nt) {
                int co = nt * 16 + l15;
                int i16 = ((kt * 3 + ky) * 32 + co) * 4 +
                          (q ^ (co & 3) ^ ((co >> 2) & 3));
                bfr[nt] = *(const short8*)(W + (size_t)i16 * 8);
            }
            #pragma unroll
            for (int dy = 0; dy < 2; ++dy) {
                int r = 4 * pyp + 2 * dy + ky;
                short8 af = (short8)0;
                if (q < 3)
                    af = *(const short8*)(S + (size_t)(r * C0_STR + 2 * oxl + q) * 8);
                #pragma unroll
                for (int nt = 0; nt < 2; ++nt)
                    acc[dy][nt] = __builtin_amdgcn_mfma_f32_16x16x32_bf16(
                        af, bfr[nt], acc[dy][nt], 0, 0, 0);
            }
        }
    };

    // software pipeline: loads for stanza k+1 in flight during compute k
    ldG(t - 1);
    stS();
    ldG(t);
    __syncthreads();
    compute(0);
    __syncthreads();
    stS();
    ldG(t + 1);
    __syncthreads();
    compute(1);
    __syncthreads();
    stS();
    __syncthreads();
    compute(2);

    unsigned short* dst = out + (size_t)bt * 32768;
    #pragma unroll
    for (int nt = 0; nt < 2; ++nt) {
        int co = nt * 16 + l15;
        float bi = biv[nt], g = gv[nt], be = bev[nt];
        #pragma unroll
        for (int j = 0; j < 2; ++j) {
            float m0 = fmaxf(fmaf(g, acc[0][nt][2 * j]     + bi, be), 0.f);
            float m1 = fmaxf(fmaf(g, acc[0][nt][2 * j + 1] + bi, be), 0.f);
            float m2 = fmaxf(fmaf(g, acc[1][nt][2 * j]     + bi, be), 0.f);
            float m3 = fmaxf(fmaf(g, acc[1][nt][2 * j + 1] + bi, be), 0.f);
            float p = fmaxf(fmaxf(m0, m1), fmaxf(m2, m3));
            int pox = xh * 16 + hx * 8 + q * 2 + j;
            int poy = yt * 4 + pyp;
            dst[(poy * 32 + pox) * 32 + co] = f2bf(p);
        }
    }
}

// ---------------------------------------------------------------------------
// Stage 1 as MFMA implicit GEMM, y-half split.
// Round 8: staging descriptors hoisted out of the kt loop (div/mod + bounds
// computed once instead of 3x).
// ---------------------------------------------------------------------------
__global__ __launch_bounds__(512) void conv1_kernel(
    const unsigned short* __restrict__ in, const unsigned short* __restrict__ w1b,
    const float* __restrict__ bias, const float* __restrict__ gam,
    const float* __restrict__ bet, unsigned short* __restrict__ out)
{
    int tid  = threadIdx.x;
    int lane = tid & 63;
    int wv   = tid >> 6;
    int q    = lane >> 4;
    int l15  = lane & 15;
    int oyp  = wv >> 1;
    int nh   = wv & 1;
    int bt = blockIdx.x >> 1, half = blockIdx.x & 1;
    int b = bt >> 5, t = bt & 31;

    __shared__ __align__(16) unsigned short S[17 * 34 * 32];
    __shared__ __align__(16) unsigned short W[9 * 64 * 32];

    f32x4 acc[2][2];
    #pragma unroll
    for (int mt = 0; mt < 2; ++mt)
        #pragma unroll
        for (int nt = 0; nt < 2; ++nt) acc[mt][nt] = (f32x4)0.f;

    // hoisted staging descriptors (kt-invariant)
    int  soff[5]; bool sok[5]; bool sact[5];
    #pragma unroll
    for (int i = 0; i < 5; ++i) {
        int e = tid + 512 * i;
        bool act = e < 17 * 34 * 4;
        int sb = e & 3;
        int pos = e >> 2;
        int ys = pos / 34, xs = pos - ys * 34;
        int g = sb ^ ((xs >> 1) & 3);
        int y = 16 * half + ys - 1, x = xs - 1;
        sact[i] = act;
        sok[i]  = act && y >= 0 && x >= 0 && x < 32;
        soff[i] = (y * 32 + x) * 32 + g * 8;
    }

    for (int kt = 0; kt < 3; ++kt) {
        int ts = t + kt - 1;
        if (ts < 0 || ts >= Tn) continue;
        __syncthreads();
        const unsigned short* src = in + (size_t)(b * Tn + ts) * 32768;
        #pragma unroll
        for (int i = 0; i < 5; ++i) {
            if (sact[i]) {
                ushort8 v = (ushort8)0;
                if (sok[i]) v = *(const ushort8*)(src + soff[i]);
                *(ushort8*)(S + (size_t)(tid + 512 * i) * 8) = v;
            }
        }
        {
            const uint4* wsrc = (const uint4*)(w1b + kt * 18432);
            uint4* wdst = (uint4*)W;
            for (int e = tid; e < 2304; e += 512) wdst[e] = wsrc[e];
        }
        __syncthreads();

        for (int k9 = 0; k9 < 9; ++k9) {
            int ky = k9 / 3, kx = k9 - ky * 3;
            short8 bf[2];
            #pragma unroll
            for (int nt = 0; nt < 2; ++nt) {
                int co = nh * 32 + nt * 16 + l15;
                int blk = (k9 * 64 + co) * 4 + (q ^ (co & 3));
                bf[nt] = *(const short8*)(W + blk * 8);
            }
            short8 af[2];
            #pragma unroll
            for (int mt = 0; mt < 2; ++mt) {
                int oyl = 2 * oyp + mt;
                int ys = 2 * oyl + ky;
                int xs = 2 * l15 + kx;
                int blk = (ys * 34 + xs) * 4 + (q ^ ((xs >> 1) & 3));
                af[mt] = *(const short8*)(S + blk * 8);
            }
            #pragma unroll
            for (int mt = 0; mt < 2; ++mt)
                #pragma unroll
                for (int nt = 0; nt < 2; ++nt)
                    acc[mt][nt] = __builtin_amdgcn_mfma_f32_16x16x32_bf16(
                        af[mt], bf[nt], acc[mt][nt], 0, 0, 0);
        }
    }

    unsigned short* dst = out + (size_t)bt * 4096;
    #pragma unroll
    for (int nt = 0; nt < 2; ++nt) {
        int co = nh * 32 + nt * 16 + l15;
        float bi = bias[co], g = gam[co], be = bet[co];
        #pragma unroll
        for (int j = 0; j < 2; ++j) {
            float m0 = fmaxf(fmaf(g, acc[0][nt][2 * j]     + bi, be), 0.f);
            float m1 = fmaxf(fmaf(g, acc[0][nt][2 * j + 1] + bi, be), 0.f);
            float m2 = fmaxf(fmaf(g, acc[1][nt][2 * j]     + bi, be), 0.f);
            float m3 = fmaxf(fmaf(g, acc[1][nt][2 * j + 1] + bi, be), 0.f);
            float p = fmaxf(fmaxf(m0, m1), fmaxf(m2, m3));
            int px = 2 * q + j, py = half * 4 + oyp;
            dst[(py * 8 + px) * 64 + co] = f2bf(p);
        }
    }
}

// ---------------------------------------------------------------------------
// Stage 2 as MFMA implicit GEMM.
// Round 8: co-split in half. Grid 512 (bt x co-half), block 192 (3 waves).
// W LDS halves (34.5 KB) -> 3 blocks/CU (9 waves) instead of 1 block (6).
// Math order per output unchanged (bit-identical).
// ---------------------------------------------------------------------------
__global__ __launch_bounds__(192) void conv2_kernel(
    const unsigned short* __restrict__ in, const unsigned short* __restrict__ w2b,
    const float* __restrict__ bias, const float* __restrict__ gam,
    const float* __restrict__ bet, float* __restrict__ out)
{
    int tid  = threadIdx.x;
    int lane = tid & 63;
    int wv   = tid >> 6;          // 0..2
    int q    = lane >> 4;
    int l15  = lane & 15;
    int bt = blockIdx.x >> 1, ch = blockIdx.x & 1;
    int b = bt >> 5, t = bt & 31;

    __shared__ __align__(16) unsigned short W[432 * 5 * 8];   // 9 k9 x 48 co
    __shared__ __align__(16) unsigned short S[81 * 5 * 8];

    f32x4 acc = (f32x4)0.f;

    for (int kt = 0; kt < 3; ++kt) {
        int ts = t + kt - 1;
        if (ts < 0 || ts >= Tn) continue;
        for (int h = 0; h < 2; ++h) {
            __syncthreads();
            const unsigned short* wsrc = w2b + (size_t)((kt * 2 + h) * 9) * 96 * 32;
            for (int e = tid; e < 1728; e += 192) {
                int r48 = e >> 2, qq = e & 3;
                int k9 = r48 / 48, cr = r48 - k9 * 48;
                uint4 v = *(const uint4*)(wsrc + (k9 * 96 + ch * 48 + cr) * 32 + qq * 8);
                *(uint4*)(W + (r48 * 5 + qq) * 8) = v;
            }
            const unsigned short* src = in + (size_t)(b * Tn + ts) * 4096 + h * 32;
            for (int e = tid; e < 324; e += 192) {
                int cb = e & 3, p = e >> 2;
                int ys = p / 9, xs = p - ys * 9;
                int y = ys - 1, x = xs - 1;
                ushort8 v = (ushort8)0;
                if (y >= 0 && x >= 0 && y < 8 && x < 8)
                    v = *(const ushort8*)(src + ((y * 8 + x) * 64 + cb * 8));
                *(ushort8*)(S + (size_t)(p * 5 + cb) * 8) = v;
            }
            __syncthreads();

            int oy = l15 >> 2, ox = l15 & 3;
            #pragma unroll
            for (int k9 = 0; k9 < 9; ++k9) {
                int ky = k9 / 3, kx = k9 - ky * 3;
                short8 bf = *(const short8*)(W + (size_t)((k9 * 48 + wv * 16 + l15) * 5 + q) * 8);
                int p = (2 * oy + ky) * 9 + (2 * ox + kx);
                short8 af = *(const short8*)(S + (size_t)(p * 5 + q) * 8);
                acc = __builtin_amdgcn_mfma_f32_16x16x32_bf16(af, bf, acc, 0, 0, 0);
            }
        }
    }

    int co = ch * 48 + wv * 16 + l15;
    float bi = bias[co], g = gam[co], be = bet[co];
    float v0 = fmaxf(fmaf(g, acc[0] + bi, be), 0.f);
    float v1 = fmaxf(fmaf(g, acc[1] + bi, be), 0.f);
    float v2 = fmaxf(fmaf(g, acc[2] + bi, be), 0.f);
    float v3 = fmaxf(fmaf(g, acc[3] + bi, be), 0.f);
    float p0 = fmaxf(v0, v1);
    float p1 = fmaxf(v2, v3);
    float r0 = fmaxf(p0, __shfl_xor(p0, 16));
    float r1 = fmaxf(p1, __shfl_xor(p1, 16));
    if ((q & 1) == 0) {
        int py = q >> 1;
        float* o = out + (size_t)(bt * 96 + co) * 4 + py * 2;
        o[0] = r0;
        o[1] = r1;
    }
}

// ---------------------------------------------------------------------------
// FUSED: GAP + ep proj + bbox MLP -> u (LDS only) -> in_proj -> xz.
// Grid 256 (token), block 256. (verified round-2/3 form)
// ---------------------------------------------------------------------------
__global__ __launch_bounds__(256) void fuse_u_inproj(
    const float* __restrict__ buf2, const float* __restrict__ epT,
    const float* __restrict__ ep_b, const float* __restrict__ bb,
    const float* __restrict__ bp1T, const float* __restrict__ bp1_b,
    const float* __restrict__ bp2T, const float* __restrict__ bp2_b,
    const float* __restrict__ ipwT, float* __restrict__ xzb)
{
    int bt = blockIdx.x;
    int m  = threadIdx.x;
    __shared__ float hs[64];
    __shared__ float gap[96];
    __shared__ float u_lds[256];
    if (m < 64) {
        float a = bp1_b[m];
        #pragma unroll
        for (int k = 0; k < 4; ++k) a = fmaf(bp1T[k * 64 + m], bb[bt * 4 + k], a);
        hs[m] = fmaxf(a, 0.f);
    } else if (m < 160) {
        int c = m - 64;
        const float* p = buf2 + ((size_t)bt * 96 + c) * 4;
        gap[c] = 0.25f * (p[0] + p[1] + p[2] + p[3]);
    }
    __syncthreads();
    float ff = ep_b[m];
    for (int c = 0; c < 96; ++c) ff = fmaf(gap[c], epT[c * 256 + m], ff);
    float bfv = bp2_b[m];
    for (int j = 0; j < 64; ++j) bfv = fmaf(hs[j], bp2T[j * 256 + m], bfv);
    u_lds[m] = ff + bfv;
    __syncthreads();

    // in_proj: outputs 4m..4m+3 (no bias)
    const float4* wbase = (const float4*)ipwT + m;    // + k*256 per row
    float4 acc = {0.f, 0.f, 0.f, 0.f};
    for (int k = 0; k < 256; ++k) {
        float uk = u_lds[k];
        float4 w4 = wbase[(size_t)k * 256];
        acc.x = fmaf(uk, w4.x, acc.x);
        acc.y = fmaf(uk, w4.y, acc.y);
        acc.z = fmaf(uk, w4.z, acc.z);
        acc.w = fmaf(uk, w4.w, acc.w);
    }
    *(float4*)(xzb + (size_t)bt * 1024 + 4 * m) = acc;
}

// ---------------------------------------------------------------------------
// FUSED: conv1d+silu -> x_proj -> dt_proj(softplus). Grid 256, block 512.
// ---------------------------------------------------------------------------
__global__ __launch_bounds__(512) void convxd_kernel(
    const float* __restrict__ xzb, const float* __restrict__ c1w,
    const float* __restrict__ c1b, const float* __restrict__ xpw,
    const float* __restrict__ dtwT, const float* __restrict__ dt_b,
    float* __restrict__ xsb, float* __restrict__ xdb, float* __restrict__ dtbf)
{
    int bt = blockIdx.x;
    int b = bt >> 5, t = bt & 31;
    int tid = threadIdx.x;
    __shared__ float xs_lds[512];
    __shared__ float xd_lds[48];

    // phase 1: depthwise causal conv1d + silu
    {
        float acc = c1b[tid];
        #pragma unroll
        for (int k = 0; k < 4; ++k) {
            int ts = t - 3 + k;
            if (ts >= 0)
                acc = fmaf(c1w[tid * 4 + k], xzb[(size_t)(b * Tn + ts) * 1024 + tid], acc);
        }
        float v = acc / (1.f + expf(-acc));
        xs_lds[tid] = v;
        xsb[(size_t)bt * 512 + tid] = v;
    }
    __syncthreads();

    // phase 2: x_proj (48 outputs), one wave per 6 outputs
    {
        int wv = tid >> 6, ln = tid & 63;
        #pragma unroll
        for (int u = 0; u < 6; ++u) {
            int o = wv * 6 + u;
            const float* wrow = xpw + (size_t)o * 512;
            float acc = 0.f;
            #pragma unroll
            for (int e = 0; e < 8; ++e)
                acc = fmaf(wrow[ln + 64 * e], xs_lds[ln + 64 * e], acc);
            acc += __shfl_xor(acc, 32); acc += __shfl_xor(acc, 16);
            acc += __shfl_xor(acc, 8);  acc += __shfl_xor(acc, 4);
            acc += __shfl_xor(acc, 2);  acc += __shfl_xor(acc, 1);
            if (ln == 0) {
                xd_lds[o] = acc;
                xdb[(size_t)bt * 48 + o] = acc;
            }
        }
    }
    __syncthreads();

    // phase 3: dt_proj + softplus
    {
        float a = dt_b[tid];
        #pragma unroll
        for (int k = 0; k < 16; ++k) a = fmaf(xd_lds[k], dtwT[k * 512 + tid], a);
        a = (a > 20.f) ? a : log1pf(expf(a));
        dtbf[(size_t)bt * 512 + tid] = a;
    }
}

// ---------------------------------------------------------------------------
// Wave-parallel selective scan (verified round 3+).
// ---------------------------------------------------------------------------
__global__ __launch_bounds__(256) void ssm_kernel(
    const float* __restrict__ xdbl, const float* __restrict__ dtb,
    const float* __restrict__ xs, const float* __restrict__ xz,
    const float* __restrict__ A_log, const float* __restrict__ Dp,
    float* __restrict__ y)
{
    int tid = threadIdx.x;
    int lane = tid & 63;
    int s = lane & 15, dsub = lane >> 4;
    int gid = blockIdx.x * 4 + (tid >> 6);
    int b = gid >> 7;
    int d = ((gid & 127) << 2) + dsub;

    float A = -expf(A_log[d * 16 + s]);
    float Dv = Dp[d];
    float h = 0.f;
    for (int t = 0; t < Tn; ++t) {
        int bt = b * Tn + t;
        float dtv = dtb[(size_t)bt * 512 + d];
        float xv  = xs [(size_t)bt * 512 + d];
        float Bs  = xdbl[(size_t)bt * 48 + 16 + s];
        float Cs  = xdbl[(size_t)bt * 48 + 32 + s];
        float dA = expf(dtv * A);
        h = fmaf(dA, h, dtv * Bs * xv);
        float c = h * Cs;
        c += __shfl_xor(c, 8, 16);
        c += __shfl_xor(c, 4, 16);
        c += __shfl_xor(c, 2, 16);
        c += __shfl_xor(c, 1, 16);
        if (s == 0) {
            float zv = xz[(size_t)bt * 1024 + 512 + d];
            float sig = 1.f / (1.f + expf(-zv));
            y[(size_t)bt * 512 + d] = (c + Dv * xv) * (zv * sig);
        }
    }
}

// ---------------------------------------------------------------------------
// FUSED: out_proj -> h1(relu) -> h2(sigmoid) -> meas. Grid 256, block 256.
// ---------------------------------------------------------------------------
__global__ __launch_bounds__(256) void out_head_kernel(
    const float* __restrict__ yb, const float* __restrict__ opwT,
    const float* __restrict__ h1wT, const float* __restrict__ h1_b,
    const float* __restrict__ h2w, const float* __restrict__ h2_b,
    float* __restrict__ meas_out)
{
    int bt = blockIdx.x;
    int m  = threadIdx.x;
    __shared__ float y_lds[512];
    __shared__ float mo_lds[256];
    __shared__ float hid_lds[128];

    y_lds[m]       = yb[(size_t)bt * 512 + m];
    y_lds[m + 256] = yb[(size_t)bt * 512 + m + 256];
    __syncthreads();

    {   // out_proj (no bias)
        float a = 0.f;
        for (int k = 0; k < 512; ++k) a = fmaf(y_lds[k], opwT[k * 256 + m], a);
        mo_lds[m] = a;
    }
    __syncthreads();

    if (m < 128) {  // h1 + relu
        float a = h1_b[m];
        for (int k = 0; k < 256; ++k) a = fmaf(mo_lds[k], h1wT[k * 128 + m], a);
        hid_lds[m] = fmaxf(a, 0.f);
    }
    __syncthreads();

    if (m < 64) {   // h2 + sigmoid: 4 outputs x 16 lanes
        int o2 = m >> 4, l15 = m & 15;
        float acc = 0.f;
        #pragma unroll
        for (int e = 0; e < 8; ++e)
            acc = fmaf(h2w[o2 * 128 + l15 + 16 * e], hid_lds[l15 + 16 * e], acc);
        acc += __shfl_xor(acc, 8, 16);
        acc += __shfl_xor(acc, 4, 16);
        acc += __shfl_xor(acc, 2, 16);
        acc += __shfl_xor(acc, 1, 16);
        if (l15 == 0) {
            float a = acc + h2_b[o2];
            meas_out[bt * 4 + o2] = 1.f / (1.f + expf(-a));
        }
    }
}

// ---------------------------------------------------------------------------
// Kalman state recurrence only (gains precomputed in prep_all).
// ---------------------------------------------------------------------------
__global__ __launch_bounds__(128) void kf_kernel(
    const float* __restrict__ meas, const float* __restrict__ bb,
    const float* __restrict__ Fin, const float* __restrict__ Hmin,
    const float* __restrict__ kfK, float* __restrict__ pred)
{
    int tid = threadIdx.x;
    int b   = tid >> 4;            // 0..7
    int l16 = tid & 15;
    int i = l16 >> 2, j = l16 & 3;
    int gb = tid & 48;             // 16-group base within wave

    float Fv = Fin[l16], Hv = Hmin[l16];
    float sv = bb[b * 128 + j];            // s[j] replicated across i

    for (int t = 0; t < Tn; ++t) {
        float mv = meas[(b * Tn + t) * 4 + j];           // m[j]
        float Kv = kfK[t * 16 + l16];
        float tr = Fv * sv;
        tr += __shfl_xor(tr, 1); tr += __shfl_xor(tr, 2);
        float spv = tr;
        float spj = __shfl(spv, gb + j * 4, 64);
        float hsp = Hv * spj;
        hsp += __shfl_xor(hsp, 1); hsp += __shfl_xor(hsp, 2);
        float yrv = mv - __shfl(hsp, gb + j * 4, 64);
        float t3 = Kv * yrv;
        t3 += __shfl_xor(t3, 1); t3 += __shfl_xor(t3, 2);
        float snv = spv + t3;
        if (j == 0) pred[(b * Tn + t) * 4 + i] = snv;
        sv = __shfl(snv, gb + j * 4, 64);
    }
}

// ---------------------------------------------------------------------------
extern "C" void kernel_launch(void* const* d_in, const int* in_sizes, int n_in,
                              void* d_out, int out_size, void* d_ws, size_t ws_size,
                              hipStream_t stream)
{
    const float* frames = (const float*)d_in[0];
    const float* bb     = (const float*)d_in[1];
    const float* cw0 = (const float*)d_in[2],  *cb0 = (const float*)d_in[3];
    const float* g0  = (const float*)d_in[4],  *be0 = (const float*)d_in[5];
    const float* cw1 = (const float*)d_in[6],  *cb1 = (const float*)d_in[7];
    const float* g1  = (const float*)d_in[8],  *be1 = (const float*)d_in[9];
    const float* cw2 = (const float*)d_in[10], *cb2 = (const float*)d_in[11];
    const float* g2  = (const float*)d_in[12], *be2 = (const float*)d_in[13];
    const float* ep_w  = (const float*)d_in[14], *ep_b  = (const float*)d_in[15];
    const float* bp1_w = (const float*)d_in[16], *bp1_b = (const float*)d_in[17];
    const float* bp2_w = (const float*)d_in[18], *bp2_b = (const float*)d_in[19];
    const float* in_proj_w = (const float*)d_in[20];
    const float* c1w = (const float*)d_in[21], *c1b = (const float*)d_in[22];
    const float* x_proj_w = (const float*)d_in[23];
    const float* dt_w = (const float*)d_in[24], *dt_b = (const float*)d_in[25];
    const float* A_log = (const float*)d_in[26], *Dp = (const float*)d_in[27];
    const float* out_proj_w = (const float*)d_in[28];
    const float* h1_w = (const float*)d_in[29], *h1_b = (const float*)d_in[30];
    const float* h2_w = (const float*)d_in[31], *h2_b = (const float*)d_in[32];
    const float* kfF = (const float*)d_in[33], *kfH = (const float*)d_in[34];
    const float* kfq = (const float*)d_in[35], *kfr = (const float*)d_in[36];

    // workspace layout
    float* ws   = (float*)d_ws;
    float* buf2 = ws;                        // (256,96,2,2)   98304
    float* xzb  = buf2 + 98304;              // (256,1024)    262144
    float* xsb  = xzb  + 262144;             // (256,512)     131072
    float* xdb  = xsb  + 131072;             // (256,48)       12288
    float* dtbf = xdb  + 12288;              // (256,512)     131072
    float* yb   = dtbf + 131072;             // (256,512)     131072
    float* tW   = yb   + 131072;             // transposed weights 500480
    float* kfK  = tW + 500480;               // (32,16) KF gains      512
    unsigned short* buf0b = (unsigned short*)(kfK + 512);    // bf16 (256,32,32,32)
    unsigned short* buf1b = buf0b + 8388608;                 // bf16 (256,8,8,64)
    unsigned short* w2b   = buf1b + 131072;
    unsigned short* w1b   = w2b + 165888;
    unsigned short* w0b   = w1b + 55296;

    float* ipwT = tW;
    float* dtwT = tW + 286720;
    float* opwT = tW + 294912;
    float* h1wT = tW + 425984;
    float* epwT = tW + 459264;
    float* bp2T = tW + 483840;
    float* bp1T = tW + 500224;

    float* kf_out   = (float*)d_out;          // (8,32,4)
    float* meas_out = kf_out + Bn * Tn * 4;   // (8,32,4)

    // 730880/256 = 2855 copy blocks + 1 KF-gain block
    prep_all<<<dim3(2856), 256, 0, stream>>>(cw0, cw1, cw2,
                                             in_proj_w, x_proj_w, dt_w, out_proj_w,
                                             h1_w, h2_w, ep_w, bp2_w, bp1_w,
                                             kfF, kfH, kfq, kfr,
                                             w0b, w1b, w2b, tW, kfK);

    conv0_kernel<<<dim3(4096), 512, 0, stream>>>(frames, w0b, cb0, g0, be0, buf0b);
    conv1_kernel<<<dim3(512), 512, 0, stream>>>(buf0b, w1b, cb1, g1, be1, buf1b);
    conv2_kernel<<<dim3(512), 192, 0, stream>>>(buf1b, w2b, cb2, g2, be2, buf2);

    fuse_u_inproj<<<dim3(256), 256, 0, stream>>>(buf2, epwT, ep_b, bb, bp1T, bp1_b,
                                                 bp2T, bp2_b, ipwT, xzb);
    convxd_kernel<<<dim3(256), 512, 0, stream>>>(xzb, c1w, c1b, x_proj_w,
                                                 dtwT, dt_b, xsb, xdb, dtbf);
    ssm_kernel<<<dim3(256), 256, 0, stream>>>(xdb, dtbf, xsb, xzb, A_log, Dp, yb);
    out_head_kernel<<<dim3(256), 256, 0, stream>>>(yb, opwT, h1wT, h1_b,
                                                   h2_w, h2_b, meas_out);
    kf_kernel<<<dim3(1), 128, 0, stream>>>(meas_out, bb, kfF, kfH, kfK, kf_out);
}